// Round 10
// baseline (492.583 us; speedup 1.0000x reference)
//
#include <hip/hip_runtime.h>

// CombinedLoss: 0.7*MSE + 0.3*mean_b softDTW_gamma.  B=64, T=1024, C=8, fp32.
// R10: strip-mined column sweep, 4 rows/lane, ONE WAVE PER BLOCK.
// 256 blocks x 64 thr = 4 bands/batch; lane l owns rows q*256+4l..+3 and at
// step s processes column j=s-l (4 cells chained in registers). Per step:
// 1 DPP (row boundary from lane l-1), 9 planar LDS t-reads (stride-1, free),
// 4 cells of exact softmin. Amortizes the ~300cyc/step fixed cost over 4 cells
// (R4/R7/R9 all measured ~370-470 cyc PER CELL with 1 row/lane).
// Cross-band: R9's self-validating u64 tag rings in ws (relaxed agent atomics,
// tag=col), consumer spins per 32-step window + 1-window prefetch. No credits
// needed (rings are full-length, no wrap). Deadlock-free by construction.
// ws: [0,256) mse | [256,320) sdtw | u64 rings @ float-offset 320 (~1.58 MB).

constexpr int TT = 1024;
constexpr float ALPHA_ = 0.7f;
constexpr float FINF = 1000000000.0f;

__device__ __forceinline__ float shflup1(float old0, float v) {
    return __int_as_float(__builtin_amdgcn_update_dpp(
        __float_as_int(old0), __float_as_int(v), 0x138 /*wave_shr:1*/,
        0xf, 0xf, false));
}

__global__ __launch_bounds__(64) void sdtw_strip_kernel(
    const float* __restrict__ pred, const float* __restrict__ target,
    float* __restrict__ ws)
{
    __shared__ float s_t[9 * TT];   // planes 0..7: -2*t_c[j]; plane 8: y2[j]

    const int blk = blockIdx.x;
    const int b = blk & 63;          // batch (q-major: band pairs same XCD)
    const int q = blk >> 6;          // band 0..3
    const int l = threadIdx.x;       // lane 0..63
    const int i0 = q * 256 + 4 * l;  // first row of this lane's strip

    const float c1 = 7.213475204444817f;     // log2(e)/gamma
    const float c2 = 0.13862943611198906f;   // gamma*ln(2)

    // ---- load strip rows of pred (+target rows for MSE) ----
    float p[4][8], x2[4];
    float msep = 0.f;
    #pragma unroll
    for (int r = 0; r < 4; ++r) {
        const float* pr = pred   + ((size_t)b * TT + i0 + r) * 8;
        const float* tr = target + ((size_t)b * TT + i0 + r) * 8;
        const float4 a0 = ((const float4*)pr)[0];
        const float4 a1 = ((const float4*)pr)[1];
        const float4 t0 = ((const float4*)tr)[0];
        const float4 t1 = ((const float4*)tr)[1];
        const float pp[8] = {a0.x,a0.y,a0.z,a0.w,a1.x,a1.y,a1.z,a1.w};
        const float tt[8] = {t0.x,t0.y,t0.z,t0.w,t1.x,t1.y,t1.z,t1.w};
        float xx = 0.f;
        #pragma unroll
        for (int c = 0; c < 8; ++c) {
            xx = fmaf(pp[c], pp[c], xx);
            const float d = pp[c] - tt[c];
            msep = fmaf(d, d, msep);
            p[r][c] = pp[c];
        }
        x2[r] = xx;
    }
    #pragma unroll
    for (int off = 32; off > 0; off >>= 1) msep += __shfl_down(msep, off, 64);
    if (l == 0) ws[blk] = msep;

    // ---- stage all 1024 target columns planar (16 cols per lane) ----
    const float* tg = target + (size_t)b * TT * 8;
    #pragma unroll
    for (int c0 = 0; c0 < 16; ++c0) {
        const int col = l + (c0 << 6);
        const float4 u0 = ((const float4*)(tg + (size_t)col * 8))[0];
        const float4 u1 = ((const float4*)(tg + (size_t)col * 8))[1];
        s_t[0*TT+col] = -2.f*u0.x; s_t[1*TT+col] = -2.f*u0.y;
        s_t[2*TT+col] = -2.f*u0.z; s_t[3*TT+col] = -2.f*u0.w;
        s_t[4*TT+col] = -2.f*u1.x; s_t[5*TT+col] = -2.f*u1.y;
        s_t[6*TT+col] = -2.f*u1.z; s_t[7*TT+col] = -2.f*u1.w;
        s_t[8*TT+col] = u0.x*u0.x + u0.y*u0.y + u0.z*u0.z + u0.w*u0.w
                      + u1.x*u1.x + u1.y*u1.y + u1.z*u1.z + u1.w*u1.w;
    }
    __syncthreads();   // single wave: ~free; guarantees LDS visibility

    // ---- cross-band tag rings ----
    unsigned long long* rings = (unsigned long long*)(ws + 320);
    unsigned long long* pub = rings + (size_t)(q * 64 + b) * TT;        // q<3
    unsigned long long* con = rings + (size_t)((q - 1) * 64 + b) * TT;  // q>0

    // ---- DP state ----
    float lE0 = FINF, lE1 = FINF, lE2 = FINF, lE3 = FINF; // left col values
    float bottom = FINF;                                   // row i0+3, col j-1
    float upprev = (q == 0 && l == 0) ? 0.0f : FINF;       // diag feed lane0
    float hval = FINF;
    unsigned long long hpre = 0; int hpf = 0;

    #define CELLF(UPV, LEV, DGV, ACC, OUT)                                  \
    {   const float m_  = fminf(fminf(UPV, LEV), DGV);                      \
        const float M_  = fmaxf(fmaxf(UPV, LEV), DGV);                      \
        const float d_  = __builtin_amdgcn_fmed3f(UPV, LEV, DGV);           \
        const float mc_ = m_ * c1;                                          \
        const float e1_ = __builtin_amdgcn_exp2f(fmaf(d_, -c1, mc_));       \
        const float e2_ = __builtin_amdgcn_exp2f(fmaf(M_, -c1, mc_));       \
        const float lg_ = __builtin_amdgcn_logf(1.0f + (e1_ + e2_));        \
        OUT = ACC + fmaf(-c2, lg_, m_); }

    for (int u = 0; u < 34; ++u) {                 // 34 windows x 32 steps
        const int S0 = u << 5;

        // ---- acquire halo window (cols S0..S0+31 of row i0-1) ----
        if (q > 0) {
            const int col = S0 + l;
            const bool need = (l < 32) && (col <= TT - 1);
            const int idx = min(col, TT - 1);
            unsigned long long e;
            if (hpf) { e = hpre; hpf = 0; }
            else e = __hip_atomic_load(con + idx, __ATOMIC_RELAXED,
                                       __HIP_MEMORY_SCOPE_AGENT);
            while (!__all((!need) | ((int)(e >> 32) == col)))
                e = __hip_atomic_load(con + idx, __ATOMIC_RELAXED,
                                      __HIP_MEMORY_SCOPE_AGENT);
            hval = need ? __uint_as_float((unsigned)e) : FINF;
            if (u < 33) {                           // prefetch next window
                const int coln = S0 + 32 + l;
                hpre = __hip_atomic_load(con + min(coln, TT - 1),
                                         __ATOMIC_RELAXED,
                                         __HIP_MEMORY_SCOPE_AGENT);
                hpf = 1;
            }
        }

        if (u >= 2 && u <= 31) {
            // ---- interior: all lanes active, no clamps/selects ----
            #pragma unroll 4
            for (int d = 0; d < 32; ++d) {
                const int s = S0 + d;
                const int jv = s - l;
                const float hs = (q > 0)
                    ? __int_as_float(__builtin_amdgcn_readlane(
                          __float_as_int(hval), d))
                    : FINF;
                const float up_in = shflup1(hs, bottom);
                float t0=s_t[jv],      t1=s_t[TT+jv],   t2=s_t[2*TT+jv],
                      t3=s_t[3*TT+jv], t4=s_t[4*TT+jv], t5=s_t[5*TT+jv],
                      t6=s_t[6*TT+jv], t7=s_t[7*TT+jv], yv=s_t[8*TT+jv];
                float a0, a1s, a2s, a3s;
                #define DOT(R, OUT)                                          \
                {   float ac = x2[R] + yv;                                   \
                    ac = fmaf(p[R][0],t0,ac); ac = fmaf(p[R][1],t1,ac);      \
                    ac = fmaf(p[R][2],t2,ac); ac = fmaf(p[R][3],t3,ac);      \
                    ac = fmaf(p[R][4],t4,ac); ac = fmaf(p[R][5],t5,ac);      \
                    ac = fmaf(p[R][6],t6,ac); ac = fmaf(p[R][7],t7,ac);      \
                    OUT = ac; }
                DOT(0, a0) DOT(1, a1s) DOT(2, a2s) DOT(3, a3s)
                float n0, n1, n2, n3;
                CELLF(up_in, lE0, upprev, a0,  n0)
                CELLF(n0,    lE1, lE0,    a1s, n1)
                CELLF(n1,    lE2, lE1,    a2s, n2)
                CELLF(n2,    lE3, lE2,    a3s, n3)
                upprev = up_in;
                lE0 = n0; lE1 = n1; lE2 = n2; lE3 = n3; bottom = n3;
                if (q < 3) {
                    if (l == 63) {
                        const int kk = s - 63;
                        const unsigned long long ev =
                            ((unsigned long long)(unsigned)kk << 32) |
                            (unsigned long long)__float_as_uint(n3);
                        __hip_atomic_store(pub + kk, ev, __ATOMIC_RELAXED,
                                           __HIP_MEMORY_SCOPE_AGENT);
                    }
                }
                #undef DOT
            }
        } else {
            // ---- edge windows: activity + clamp + select ----
            for (int d = 0; d < 32; ++d) {
                const int s = S0 + d;
                if (s > 2 * TT - 2 - 960 + 21) { /* s > 1086 */ }
                if (s > 1086) break;
                const int jv = s - l;
                const int jc = min(max(jv, 0), TT - 1);
                const bool act = (jv >= 0) && (jv <= TT - 1);
                const float hs = (q > 0)
                    ? __int_as_float(__builtin_amdgcn_readlane(
                          __float_as_int(hval), d))
                    : FINF;
                const float up_in = shflup1(hs, bottom);
                float t0=s_t[jc],      t1=s_t[TT+jc],   t2=s_t[2*TT+jc],
                      t3=s_t[3*TT+jc], t4=s_t[4*TT+jc], t5=s_t[5*TT+jc],
                      t6=s_t[6*TT+jc], t7=s_t[7*TT+jc], yv=s_t[8*TT+jc];
                float a0, a1s, a2s, a3s;
                #define DOT(R, OUT)                                          \
                {   float ac = x2[R] + yv;                                   \
                    ac = fmaf(p[R][0],t0,ac); ac = fmaf(p[R][1],t1,ac);      \
                    ac = fmaf(p[R][2],t2,ac); ac = fmaf(p[R][3],t3,ac);      \
                    ac = fmaf(p[R][4],t4,ac); ac = fmaf(p[R][5],t5,ac);      \
                    ac = fmaf(p[R][6],t6,ac); ac = fmaf(p[R][7],t7,ac);      \
                    OUT = ac; }
                DOT(0, a0) DOT(1, a1s) DOT(2, a2s) DOT(3, a3s)
                float n0, n1, n2, n3;
                CELLF(up_in, lE0, upprev, a0,  n0)
                CELLF(n0,    lE1, lE0,    a1s, n1)
                CELLF(n1,    lE2, lE1,    a2s, n2)
                CELLF(n2,    lE3, lE2,    a3s, n3)
                upprev = up_in;
                lE0 = act ? n0 : lE0;  lE1 = act ? n1 : lE1;
                lE2 = act ? n2 : lE2;  lE3 = act ? n3 : lE3;
                bottom = act ? n3 : bottom;
                if (q < 3 && s >= 63) {
                    if (l == 63) {
                        const int kk = s - 63;
                        const unsigned long long ev =
                            ((unsigned long long)(unsigned)kk << 32) |
                            (unsigned long long)__float_as_uint(bottom);
                        __hip_atomic_store(pub + kk, ev, __ATOMIC_RELAXED,
                                           __HIP_MEMORY_SCOPE_AGENT);
                    }
                }
                #undef DOT
            }
        }
    }
    #undef CELLF

    if (q == 3 && l == 63) ws[256 + b] = lE3;    // R[1023][1023]
}

__global__ __launch_bounds__(256) void finalize2_kernel(
    const float* __restrict__ ws, float* __restrict__ out)
{
    __shared__ float sm[4], ss[4];
    const int tid = threadIdx.x, l = tid & 63, w = tid >> 6;
    float m  = ws[tid];
    float sd = (tid < 64) ? ws[256 + tid] : 0.f;
    #pragma unroll
    for (int off = 32; off > 0; off >>= 1) {
        m  += __shfl_down(m,  off, 64);
        sd += __shfl_down(sd, off, 64);
    }
    if (l == 0) { sm[w] = m; ss[w] = sd; }
    __syncthreads();
    if (tid == 0) {
        float M = sm[0] + sm[1] + sm[2] + sm[3];
        float S = ss[0] + ss[1] + ss[2] + ss[3];
        out[0] = ALPHA_ * (M / 524288.0f) + (1.0f - ALPHA_) * (S / 64.0f);
    }
}

extern "C" void kernel_launch(void* const* d_in, const int* in_sizes, int n_in,
                              void* d_out, int out_size, void* d_ws, size_t ws_size,
                              hipStream_t stream) {
    const float* pred   = (const float*)d_in[0];
    const float* target = (const float*)d_in[1];
    float* ws  = (float*)d_ws;
    float* out = (float*)d_out;

    sdtw_strip_kernel<<<256, 64, 0, stream>>>(pred, target, ws);
    finalize2_kernel<<<1, 256, 0, stream>>>(ws, out);
}